// Round 2
// baseline (548.876 us; speedup 1.0000x reference)
//
#include <hip/hip_runtime.h>
#include <hip/hip_bf16.h>

typedef unsigned short u16;
typedef unsigned int   u32;

#define HH 8
#define DD 128
#define KD 16
#define VD 16
#define EE 128
#define BB 64
#define GG 200
#define QT 8
#define NT 25              // GG / QT
#define GGQ (GG*GG)        // 40000
#define OUT0 (BB*GG*EE)    // 1638400 (start of route_attn region in d_out)
#define RSTRIDE (BB*GGQ)   // 2560000 (route channel stride)

// ---- ws layout (float index offsets) ----
#define OFF_FLAG 0                  // u32 dtype flag (1 = fp32 inputs)
#define OFF_WQ   16
#define OFF_WK   (OFF_WQ + 16384)
#define OFF_WV   (OFF_WK + 16384)
#define OFF_WO   (OFF_WV + 16384)
#define OFF_WM   (OFF_WO + 16384)   // 536 floats: W1|b1|W2|b2
#define OFF_H    (OFF_WM + 576)     // h_em fp32: 1,638,400
#define NPROJ    (HH*BB*GG*KD)      // 1,638,400
#define OFF_Q    (OFF_H + NPROJ)
#define OFF_K    (OFF_Q + NPROJ)
#define OFF_V    (OFF_K + NPROJ)
// total ~26.5 MB of ws

__device__ __forceinline__ float bf2f(u16 u) { return __uint_as_float(((u32)u) << 16); }
__device__ __forceinline__ u16 f2bf(float f) {
    u32 x = __float_as_uint(f);
    return (u16)((x + 0x7fffu + ((x >> 16) & 1u)) >> 16);   // RNE
}
__device__ __forceinline__ float ldin(const void* p, int idx, bool f32) {
    return f32 ? ((const float*)p)[idx] : bf2f(((const u16*)p)[idx]);
}

// ---------------- kernel 0: dtype detect + convert all weights to fp32 ----------------
__global__ __launch_bounds__(256) void detect_conv_kernel(
    const void* __restrict__ h_em,
    const void* __restrict__ Wq, const void* __restrict__ Wk, const void* __restrict__ Wv,
    const void* __restrict__ Wout,
    const void* __restrict__ W1, const void* __restrict__ b1,
    const void* __restrict__ W2, const void* __restrict__ b2,
    float* __restrict__ wsf)
{
    __shared__ int cnt;
    __shared__ int flag_s;
    const int t = threadIdx.x;
    if (t == 0) cnt = 0;
    __syncthreads();
    // Examine low u16 of the first 256 32-bit words of h_em.
    // fp32 normal data: low half = random mantissa bits -> random bf16 exponent (~83% insane).
    // bf16 data: every half is a sane bf16 value (exponent ~[100,140] or zero).
    {
        const u16 u = ((const u16*)h_em)[2 * t];
        const int e = (u >> 7) & 0xFF;
        const int insane = (e != 0 && (e < 100 || e > 140)) ? 1 : 0;
        atomicAdd(&cnt, insane);
    }
    __syncthreads();
    if (t == 0) { flag_s = (cnt > 64) ? 1 : 0; ((u32*)wsf)[OFF_FLAG] = (u32)flag_s; }
    __syncthreads();
    const bool f32 = (flag_s != 0);

    for (int i = t; i < 16384; i += 256) {
        wsf[OFF_WQ + i] = ldin(Wq,   i, f32);
        wsf[OFF_WK + i] = ldin(Wk,   i, f32);
        wsf[OFF_WV + i] = ldin(Wv,   i, f32);
        wsf[OFF_WO + i] = ldin(Wout, i, f32);
    }
    for (int i = t; i < 536; i += 256) {
        float v;
        if      (i < 384) v = ldin(W1, i,       f32);
        else if (i < 400) v = ldin(b1, i - 384, f32);
        else if (i < 528) v = ldin(W2, i - 400, f32);
        else              v = ldin(b2, i - 528, f32);
        wsf[OFF_WM + i] = v;
    }
}

// ---------------- kernel 1: convert h_em to fp32 ws ----------------
__global__ __launch_bounds__(256) void convh_kernel(const void* __restrict__ h_em,
                                                    float* __restrict__ wsf)
{
    const bool f32 = ((const u32*)wsf)[OFF_FLAG] != 0;
    const int N = BB * GG * DD;   // 1,638,400
    for (int i = blockIdx.x * 256 + threadIdx.x; i < N; i += gridDim.x * 256)
        wsf[OFF_H + i] = ldin(h_em, i, f32);
}

// ---------------- kernel 2: QKV projections (all-fp32 ws in/out) ----------------
__global__ __launch_bounds__(128) void qkv_kernel(float* __restrict__ wsf)
{
    const float* Hf  = wsf + OFF_H;
    const float* Wqf = wsf + OFF_WQ;
    const float* Wkf = wsf + OFF_WK;
    const float* Wvf = wsf + OFF_WV;
    float* Qf = wsf + OFF_Q;
    float* Kf = wsf + OFF_K;
    float* Vf = wsf + OFF_V;

    const int b  = blockIdx.x / NT;
    const int g0 = (blockIdx.x % NT) * QT;
    const int t  = threadIdx.x;

    __shared__ float xs[QT][DD];
    #pragma unroll
    for (int r = 0; r < QT; ++r)
        xs[r][t] = Hf[(b*GG + g0 + r)*DD + t];
    __syncthreads();

    const int h = t >> 4, k = t & 15;
    float aq[QT], ak[QT], av[QT];
    #pragma unroll
    for (int r = 0; r < QT; ++r) { aq[r] = 0.f; ak[r] = 0.f; av[r] = 0.f; }

    for (int i = 0; i < DD; ++i) {
        const float wq = Wqf[(h*DD + i)*KD + k];
        const float wk = Wkf[(h*DD + i)*KD + k];
        const float wv = Wvf[(h*DD + i)*KD + k];
        #pragma unroll
        for (int r = 0; r < QT; ++r) {
            const float x = xs[r][i];
            aq[r] = fmaf(x, wq, aq[r]);
            ak[r] = fmaf(x, wk, ak[r]);
            av[r] = fmaf(x, wv, av[r]);
        }
    }
    #pragma unroll
    for (int r = 0; r < QT; ++r) {
        const int o = ((h*BB + b)*GG + g0 + r)*KD + k;
        Qf[o] = aq[r]; Kf[o] = ak[r]; Vf[o] = av[r];
    }
}

// ---------------- kernel 3: fused scores + MLP + softmax + PV + Wout ----------------
__global__ __launch_bounds__(256) void synth_main(
    const float* __restrict__ wsf,
    const void* __restrict__ route,
    void* __restrict__ out)
{
    const bool F32 = ((const u32*)wsf)[OFF_FLAG] != 0;
    const float* Qf  = wsf + OFF_Q;
    const float* Kf  = wsf + OFF_K;
    const float* Vf  = wsf + OFF_V;
    const float* W1f = wsf + OFF_WM;          // [16][24]
    const float* b1f = wsf + OFF_WM + 384;    // [16]
    const float* W2f = wsf + OFF_WM + 400;    // [8][16]
    const float* b2f = wsf + OFF_WM + 528;    // [8]
    const float* Wof = wsf + OFF_WO;          // [128][128] (hv, e)

    const int tile = blockIdx.x, b = blockIdx.y;
    const int q0 = tile * QT;
    const int tid = threadIdx.x;

    __shared__ __align__(16) u16 sbuf[QT*HH*GG];    // 25.6 KB: logits [q][h][g] -> weights [h][g][q]
    __shared__ float heads_s[QT][HH*VD];            // 4 KB

    const int g = tid;
    if (g < GG) {
        // ---- Phase A: qk logits -> sbuf[q][h][g] (bf16) ----
        #pragma unroll
        for (int h = 0; h < HH; ++h) {
            const float4* kp = (const float4*)(Kf + ((h*BB + b)*GG + g)*KD);
            const float4 k0 = kp[0], k1 = kp[1], k2 = kp[2], k3 = kp[3];
            #pragma unroll
            for (int q = 0; q < QT; ++q) {
                const float* Qp = Qf + ((h*BB + b)*GG + q0 + q)*KD;   // uniform address
                float s = k0.x*Qp[0]  + k0.y*Qp[1]  + k0.z*Qp[2]  + k0.w*Qp[3]
                        + k1.x*Qp[4]  + k1.y*Qp[5]  + k1.z*Qp[6]  + k1.w*Qp[7]
                        + k2.x*Qp[8]  + k2.y*Qp[9]  + k2.z*Qp[10] + k2.w*Qp[11]
                        + k3.x*Qp[12] + k3.y*Qp[13] + k3.z*Qp[14] + k3.w*Qp[15];
                sbuf[(q*HH + h)*GG + g] = f2bf(s);
            }
        }
        // ---- Phase B: route copy + tiny MLP -> attn logits in place ----
        #pragma unroll 1
        for (int q = 0; q < QT; ++q) {
            float x[24];
            #pragma unroll
            for (int h = 0; h < HH; ++h) x[h] = bf2f(sbuf[(q*HH + h)*GG + g]);
            const int rbase = (b*GG + (q0 + q))*GG + g;
            if (F32) {
                const u32* rp = (const u32*)route;
                u32* op = (u32*)out;
                #pragma unroll
                for (int c = 0; c < 16; ++c) {
                    const u32 w = rp[rbase + c*RSTRIDE];
                    op[OUT0 + rbase + c*RSTRIDE] = w;        // fused pass-through copy
                    x[8 + c] = __uint_as_float(w);
                }
            } else {
                const u16* rp = (const u16*)route;
                u16* op = (u16*)out;
                #pragma unroll
                for (int c = 0; c < 16; ++c) {
                    const u16 u = rp[rbase + c*RSTRIDE];
                    op[OUT0 + rbase + c*RSTRIDE] = u;
                    x[8 + c] = bf2f(u);
                }
            }
            float hid[16];
            #pragma unroll
            for (int j = 0; j < 16; ++j) {
                float a = b1f[j];
                #pragma unroll
                for (int c = 0; c < 24; ++c) a = fmaf(x[c], W1f[j*24 + c], a);
                hid[j] = fmaxf(a, 0.f);
            }
            #pragma unroll
            for (int h = 0; h < HH; ++h) {
                float a = b2f[h];
                #pragma unroll
                for (int j = 0; j < 16; ++j) a = fmaf(hid[j], W2f[h*16 + j], a);
                sbuf[(q*HH + h)*GG + g] = f2bf(a);
            }
        }
    }
    __syncthreads();

    // ---- Phase C: softmax over g per (q,h); write weights transposed [h][g][q] ----
    {
        const int pair = tid >> 2, part = tid & 3;
        const int q = pair >> 3, h = pair & 7;
        const int gbase = part * 50;
        float vals[50];
        #pragma unroll
        for (int i = 0; i < 50; ++i) vals[i] = bf2f(sbuf[(q*HH + h)*GG + gbase + i]);
        float m = -1e30f;
        #pragma unroll
        for (int i = 0; i < 50; ++i) m = fmaxf(m, vals[i]);
        m = fmaxf(m, __shfl_xor(m, 1));
        m = fmaxf(m, __shfl_xor(m, 2));
        float ssum = 0.f;
        #pragma unroll
        for (int i = 0; i < 50; ++i) { vals[i] = __expf(vals[i] - m); ssum += vals[i]; }
        ssum += __shfl_xor(ssum, 1);
        ssum += __shfl_xor(ssum, 2);
        const float rs = 1.0f / ssum;
        __syncthreads();   // all reads of logit layout done before overwrite
        #pragma unroll
        for (int i = 0; i < 50; ++i)
            sbuf[(h*GG + gbase + i)*QT + q] = f2bf(vals[i] * rs);
    }
    __syncthreads();

    // ---- Phase D: heads[q][h][v] = sum_g w[h][g][q] * V[h][g][v] ----
    {
        const int strip = tid & 1, v = (tid >> 1) & 15, h = tid >> 5;
        float acc[QT];
        #pragma unroll
        for (int q = 0; q < QT; ++q) acc[q] = 0.f;
        #pragma unroll 4
        for (int i = 0; i < 100; ++i) {
            const int gg = 2*i + strip;
            const uint4 w4 = *(const uint4*)(sbuf + (h*GG + gg)*QT);
            const float vv = Vf[((h*BB + b)*GG + gg)*VD + v];
            acc[0] = fmaf(__uint_as_float(w4.x << 16),          vv, acc[0]);
            acc[1] = fmaf(__uint_as_float(w4.x & 0xffff0000u),  vv, acc[1]);
            acc[2] = fmaf(__uint_as_float(w4.y << 16),          vv, acc[2]);
            acc[3] = fmaf(__uint_as_float(w4.y & 0xffff0000u),  vv, acc[3]);
            acc[4] = fmaf(__uint_as_float(w4.z << 16),          vv, acc[4]);
            acc[5] = fmaf(__uint_as_float(w4.z & 0xffff0000u),  vv, acc[5]);
            acc[6] = fmaf(__uint_as_float(w4.w << 16),          vv, acc[6]);
            acc[7] = fmaf(__uint_as_float(w4.w & 0xffff0000u),  vv, acc[7]);
        }
        #pragma unroll
        for (int q = 0; q < QT; ++q) acc[q] += __shfl_xor(acc[q], 1);
        if (strip == 0) {
            #pragma unroll
            for (int q = 0; q < QT; ++q) heads_s[q][h*VD + v] = acc[q];
        }
    }
    __syncthreads();

    // ---- Phase E: out[b][q][e] = sum_{h,v} heads * Wout[h][v][e] ----
    {
        const int e = tid & 127, half = tid >> 7;
        float acc[4] = {0.f, 0.f, 0.f, 0.f};
        #pragma unroll 8
        for (int hv = 0; hv < 128; ++hv) {
            const float wo = Wof[hv*EE + e];
            #pragma unroll
            for (int j = 0; j < 4; ++j)
                acc[j] = fmaf(heads_s[half*4 + j][hv], wo, acc[j]);
        }
        if (F32) {
            float* op = (float*)out;
            #pragma unroll
            for (int j = 0; j < 4; ++j)
                op[(b*GG + q0 + half*4 + j)*EE + e] = acc[j];
        } else {
            u16* op = (u16*)out;
            #pragma unroll
            for (int j = 0; j < 4; ++j)
                op[(b*GG + q0 + half*4 + j)*EE + e] = f2bf(acc[j]);
        }
    }
}

extern "C" void kernel_launch(void* const* d_in, const int* in_sizes, int n_in,
                              void* d_out, int out_size, void* d_ws, size_t ws_size,
                              hipStream_t stream) {
    const void* h_em  = d_in[0];
    const void* route = d_in[1];
    const void* Wq    = d_in[2];
    const void* Wk    = d_in[3];
    const void* Wv    = d_in[4];
    const void* W1    = d_in[5];
    const void* b1    = d_in[6];
    const void* W2    = d_in[7];
    const void* b2    = d_in[8];
    const void* Wout  = d_in[9];

    float* wsf = (float*)d_ws;

    detect_conv_kernel<<<1, 256, 0, stream>>>(h_em, Wq, Wk, Wv, Wout, W1, b1, W2, b2, wsf);
    convh_kernel<<<1600, 256, 0, stream>>>(h_em, wsf);
    qkv_kernel<<<BB*NT, 128, 0, stream>>>(wsf);
    synth_main<<<dim3(NT, BB), 256, 0, stream>>>(wsf, route, d_out);
}